// Round 3
// baseline (502.906 us; speedup 1.0000x reference)
//
#include <hip/hip_runtime.h>
#include <hip/hip_bf16.h>
#include <stdint.h>

#define TT 512
#define NB 128
#define EM 256
#define UN 256

typedef short bf16x8 __attribute__((ext_vector_type(8)));
typedef float floatx4 __attribute__((ext_vector_type(4)));
typedef _Float16 h2 __attribute__((ext_vector_type(2)));

__device__ inline unsigned short f2bf(float f) {
    union { float f; uint32_t u; } v; v.f = f;
    uint32_t r = v.u + 0x7fffu + ((v.u >> 16) & 1u);
    return (unsigned short)(r >> 16);
}
__device__ inline float bf2f(unsigned short b) {
    union { uint32_t u; float f; } v; v.u = ((uint32_t)b) << 16;
    return v.f;
}

__device__ inline float dot2f(h2 a, h2 b, float c) {
#if defined(__has_builtin)
#if __has_builtin(__builtin_amdgcn_fdot2)
    return __builtin_amdgcn_fdot2(a, b, c, false);
#else
    return c + (float)a[0]*(float)b[0] + (float)a[1]*(float)b[1];
#endif
#else
    return c + (float)a[0]*(float)b[0] + (float)a[1]*(float)b[1];
#endif
}

// ---------------------------------------------------------------------------
// Kernel 1: repack W (f32 [256 u][256 e]) into MFMA B-fragment order, bf16.
// ---------------------------------------------------------------------------
__global__ void k_wfrag(const float* __restrict__ W, unsigned short* __restrict__ wfrag) {
    int idx = blockIdx.x * blockDim.x + threadIdx.x;  // 0..8191
    int lane = idx & 63;
    int tile = idx >> 6;            // kt*16 + nt
    int nt = tile & 15, kt = tile >> 4;
    int u  = nt * 16 + (lane & 15);
    int e0 = kt * 32 + (lane >> 4) * 8;
    unsigned short* dst = wfrag + (size_t)idx * 8;
    #pragma unroll
    for (int j = 0; j < 8; j++) dst[j] = f2bf(W[u * EM + e0 + j]);
}

// ---------------------------------------------------------------------------
// Kernel 2: xw[b][t][u] = sum_e emb[sent[b][t]][e] * W[u][e], bf16 out.
// (unchanged from passing R0/R1 version)
// ---------------------------------------------------------------------------
__global__ __launch_bounds__(256, 2) void k_gemm(
    const int* __restrict__ sent, const float* __restrict__ emb,
    const unsigned short* __restrict__ wfrag, unsigned short* __restrict__ xw)
{
    int w    = threadIdx.x >> 6;
    int lane = threadIdx.x & 63;
    int m  = lane & 15;
    int kg = lane >> 4;
    int row = blockIdx.x * 64 + w * 16 + m;
    int tok = sent[row];
    const float* arow = emb + (size_t)tok * EM;

    bf16x8 a[8];
    #pragma unroll
    for (int kt = 0; kt < 8; kt++) {
        const float* p = arow + kt * 32 + kg * 8;
        float4 f0 = *(const float4*)p;
        float4 f1 = *(const float4*)(p + 4);
        bf16x8 t;
        t[0] = (short)f2bf(f0.x); t[1] = (short)f2bf(f0.y);
        t[2] = (short)f2bf(f0.z); t[3] = (short)f2bf(f0.w);
        t[4] = (short)f2bf(f1.x); t[5] = (short)f2bf(f1.y);
        t[6] = (short)f2bf(f1.z); t[7] = (short)f2bf(f1.w);
        a[kt] = t;
    }

    floatx4 acc[16];
    #pragma unroll
    for (int nt = 0; nt < 16; nt++) acc[nt] = floatx4{0.f, 0.f, 0.f, 0.f};

    #pragma unroll
    for (int kt = 0; kt < 8; kt++) {
        #pragma unroll
        for (int nt = 0; nt < 16; nt++) {
            bf16x8 bfr = *(const bf16x8*)(wfrag + ((size_t)(kt * 16 + nt) * 64 + lane) * 8);
            acc[nt] = __builtin_amdgcn_mfma_f32_16x16x32_bf16(a[kt], bfr, acc[nt], 0, 0, 0);
        }
    }

    int rbase = blockIdx.x * 64 + w * 16 + (lane >> 4) * 4;
    int cbase = lane & 15;
    #pragma unroll
    for (int nt = 0; nt < 16; nt++) {
        #pragma unroll
        for (int r = 0; r < 4; r++) {
            xw[(size_t)(rbase + r) * UN + nt * 16 + cbase] = f2bf(acc[nt][r]);
        }
    }
}

// ---------------------------------------------------------------------------
// Kernel 3 (v3): per-batch RNN scan, 256 threads/block, NO k-split.
// Thread t owns unit u = t: full 256-MAC dot product per step (128 dot2).
// U row in regs (128 h2). h in LDS (f16, double-buffered); all h reads are
// same-address broadcasts (conflict-free); h write = 1 b16/thread.
// No shfl reduce. xw prefetched 2 steps ahead. 1 barrier/step.
// ---------------------------------------------------------------------------
__global__ __launch_bounds__(256, 1) void k_rnn(
    const float* __restrict__ Umat, const unsigned short* __restrict__ xw,
    const float* __restrict__ W1, const float* __restrict__ b1,
    const float* __restrict__ W2, const float* __restrict__ b2,
    float* __restrict__ out)
{
    __shared__ __align__(16) _Float16 hb[2][256];
    __shared__ float hid[32];
    const int t = threadIdx.x;   // unit index
    const int b = blockIdx.x;

    // U row t -> registers as 128 f16 pairs (one-time, L2/L3)
    h2 ureg[128];
    const float* up = Umat + (size_t)t * UN;
    #pragma unroll
    for (int i = 0; i < 64; i++) {
        float4 f = *(const float4*)(up + 4 * i);
        h2 p0; p0[0] = (_Float16)f.x; p0[1] = (_Float16)f.y;
        h2 p1; p1[0] = (_Float16)f.z; p1[1] = (_Float16)f.w;
        ureg[2 * i]     = p0;
        ureg[2 * i + 1] = p1;
    }

    hb[0][t] = (_Float16)0.f;
    hb[1][t] = (_Float16)0.f;
    __syncthreads();

    const unsigned short* xp = xw + (size_t)b * TT * UN + t;
    unsigned short x0 = xp[0];
    unsigned short x1 = xp[UN];
    int cur = 0;

    const float c3 = -0.33333334f, c5 = 0.13333334f, c7 = -0.05396825f, c9 = 0.02186949f;

    for (int s = 0; s < TT; s++) {
        int sn = (s + 2 < TT) ? s + 2 : TT - 1;
        unsigned short x2 = xp[(size_t)sn * UN];

        const uint4* hp4 = (const uint4*)hb[cur];
        float a0 = 0.f, a1 = 0.f, a2 = 0.f, a3 = 0.f;
        #pragma unroll
        for (int c = 0; c < 32; c++) {
            uint4 q = hp4[c];            // all-lane broadcast, conflict-free
            h2 hh0, hh1, hh2, hh3;
            *(uint32_t*)&hh0 = q.x; *(uint32_t*)&hh1 = q.y;
            *(uint32_t*)&hh2 = q.z; *(uint32_t*)&hh3 = q.w;
            a0 = dot2f(ureg[4 * c + 0], hh0, a0);
            a1 = dot2f(ureg[4 * c + 1], hh1, a1);
            a2 = dot2f(ureg[4 * c + 2], hh2, a2);
            a3 = dot2f(ureg[4 * c + 3], hh3, a3);
        }

        float z = bf2f(x0) + ((a0 + a1) + (a2 + a3));

        float hn;
        if (__builtin_expect(fabsf(z) > 0.75f, 0)) {
            float e = __expf(2.f * z);
            hn = 1.f - 2.f * __builtin_amdgcn_rcpf(e + 1.f);
        } else {
            float x2f = z * z;
            float p = fmaf(x2f, c9, c7);
            p = fmaf(x2f, p, c5);
            p = fmaf(x2f, p, c3);
            hn = fmaf(z * x2f, p, z);
        }

        hb[cur ^ 1][t] = (_Float16)hn;
        __syncthreads();
        cur ^= 1;
        x0 = x1;
        x1 = x2;
    }

    // ---- head: hidden = relu(h @ W1 + b1); logits; softmax
    if (t < 32) {
        float a = b1[t];
        for (int k = 0; k < 256; k++) a += (float)hb[cur][k] * W1[k * 32 + t];
        hid[t] = fmaxf(a, 0.f);
    }
    __syncthreads();
    if (t == 0) {
        float l0 = b2[0], l1 = b2[1];
        #pragma unroll
        for (int i = 0; i < 32; i++) {
            float hv = hid[i];
            l0 += hv * W2[2 * i];
            l1 += hv * W2[2 * i + 1];
        }
        float mx2 = fmaxf(l0, l1);
        float e0 = __expf(l0 - mx2), e1 = __expf(l1 - mx2);
        float inv = 1.f / (e0 + e1);
        out[2 * b]     = e0 * inv;
        out[2 * b + 1] = e1 * inv;
    }
}

extern "C" void kernel_launch(void* const* d_in, const int* in_sizes, int n_in,
                              void* d_out, int out_size, void* d_ws, size_t ws_size,
                              hipStream_t stream) {
    const int*   sent = (const int*)d_in[0];
    const float* emb  = (const float*)d_in[1];
    const float* W    = (const float*)d_in[2];
    const float* U    = (const float*)d_in[3];
    const float* W1   = (const float*)d_in[4];
    const float* b1   = (const float*)d_in[5];
    const float* W2   = (const float*)d_in[6];
    const float* b2   = (const float*)d_in[7];
    float* out = (float*)d_out;

    unsigned short* xw    = (unsigned short*)d_ws;                          // 32 MB bf16 [B][T][U]
    unsigned short* wfrag = (unsigned short*)((char*)d_ws + (size_t)NB * TT * UN * 2);  // 128 KB

    k_wfrag<<<32, 256, 0, stream>>>(W, wfrag);
    k_gemm<<<(NB * TT) / 64, 256, 0, stream>>>(sent, emb, wfrag, xw);
    k_rnn<<<NB, 256, 0, stream>>>(U, xw, W1, b1, W2, b2, out);
}

// Round 4
// 359.008 us; speedup vs baseline: 1.4008x; 1.4008x over previous
//
#include <hip/hip_runtime.h>
#include <hip/hip_bf16.h>
#include <stdint.h>

#define TT 512
#define NB 128
#define EM 256
#define UN 256

typedef short bf16x8 __attribute__((ext_vector_type(8)));
typedef float floatx4 __attribute__((ext_vector_type(4)));
typedef _Float16 half8 __attribute__((ext_vector_type(8)));

__device__ inline unsigned short f2bf(float f) {
    union { float f; uint32_t u; } v; v.f = f;
    uint32_t r = v.u + 0x7fffu + ((v.u >> 16) & 1u);
    return (unsigned short)(r >> 16);
}
__device__ inline float bf2f(unsigned short b) {
    union { uint32_t u; float f; } v; v.u = ((uint32_t)b) << 16;
    return v.f;
}

// ---------------------------------------------------------------------------
// Kernel 1a: repack W (f32 [256 u][256 e]) -> MFMA B-frag order, bf16 (for k_gemm)
// ---------------------------------------------------------------------------
__global__ void k_wfrag(const float* __restrict__ W, unsigned short* __restrict__ wfrag) {
    int idx = blockIdx.x * blockDim.x + threadIdx.x;  // 0..8191
    int lane = idx & 63;
    int tile = idx >> 6;            // kt*16 + nt
    int nt = tile & 15, kt = tile >> 4;
    int u  = nt * 16 + (lane & 15);
    int e0 = kt * 32 + (lane >> 4) * 8;
    unsigned short* dst = wfrag + (size_t)idx * 8;
    #pragma unroll
    for (int j = 0; j < 8; j++) dst[j] = f2bf(W[u * EM + e0 + j]);
}

// ---------------------------------------------------------------------------
// Kernel 1b: repack U (f32 [256 u][256 k]) -> MFMA B-frag order, f16 (for k_rnn)
// ufrag[(kt*16+nt)*64+lane][j] = (f16) U[nt*16+(lane&15)][kt*32+(lane>>4)*8+j]
// ---------------------------------------------------------------------------
__global__ void k_ufrag(const float* __restrict__ U, _Float16* __restrict__ ufrag) {
    int idx = blockIdx.x * blockDim.x + threadIdx.x;  // 0..8191
    int lane = idx & 63;
    int tile = idx >> 6;
    int nt = tile & 15, kt = tile >> 4;
    int u  = nt * 16 + (lane & 15);
    int k0 = kt * 32 + (lane >> 4) * 8;
    _Float16* dst = ufrag + (size_t)idx * 8;
    #pragma unroll
    for (int j = 0; j < 8; j++) dst[j] = (_Float16)U[u * UN + k0 + j];
}

// ---------------------------------------------------------------------------
// Kernel 2: xw[b][t][u] = sum_e emb[sent[b][t]][e] * W[u][e], bf16 out.
// (unchanged from passing version)
// ---------------------------------------------------------------------------
__global__ __launch_bounds__(256, 2) void k_gemm(
    const int* __restrict__ sent, const float* __restrict__ emb,
    const unsigned short* __restrict__ wfrag, unsigned short* __restrict__ xw)
{
    int w    = threadIdx.x >> 6;
    int lane = threadIdx.x & 63;
    int m  = lane & 15;
    int kg = lane >> 4;
    int row = blockIdx.x * 64 + w * 16 + m;
    int tok = sent[row];
    const float* arow = emb + (size_t)tok * EM;

    bf16x8 a[8];
    #pragma unroll
    for (int kt = 0; kt < 8; kt++) {
        const float* p = arow + kt * 32 + kg * 8;
        float4 f0 = *(const float4*)p;
        float4 f1 = *(const float4*)(p + 4);
        bf16x8 t;
        t[0] = (short)f2bf(f0.x); t[1] = (short)f2bf(f0.y);
        t[2] = (short)f2bf(f0.z); t[3] = (short)f2bf(f0.w);
        t[4] = (short)f2bf(f1.x); t[5] = (short)f2bf(f1.y);
        t[6] = (short)f2bf(f1.z); t[7] = (short)f2bf(f1.w);
        a[kt] = t;
    }

    floatx4 acc[16];
    #pragma unroll
    for (int nt = 0; nt < 16; nt++) acc[nt] = floatx4{0.f, 0.f, 0.f, 0.f};

    #pragma unroll
    for (int kt = 0; kt < 8; kt++) {
        #pragma unroll
        for (int nt = 0; nt < 16; nt++) {
            bf16x8 bfr = *(const bf16x8*)(wfrag + ((size_t)(kt * 16 + nt) * 64 + lane) * 8);
            acc[nt] = __builtin_amdgcn_mfma_f32_16x16x32_bf16(a[kt], bfr, acc[nt], 0, 0, 0);
        }
    }

    int rbase = blockIdx.x * 64 + w * 16 + (lane >> 4) * 4;
    int cbase = lane & 15;
    #pragma unroll
    for (int nt = 0; nt < 16; nt++) {
        #pragma unroll
        for (int r = 0; r < 4; r++) {
            xw[(size_t)(rbase + r) * UN + nt * 16 + cbase] = f2bf(acc[nt][r]);
        }
    }
}

// ---------------------------------------------------------------------------
// Kernel 3 (v4): per-batch RNN scan on the MATRIX pipe.
// 128 blocks x 256 threads. Wave w owns units 64w..64w+63 (N-tiles 4w..4w+3).
// U B-frags in registers (32 frags, loop-invariant). Per step:
//   A[m][k] = h[k] (all m): 8 ds_read_b128 broadcast A-frags from LDS
//   32 x mfma_f32_16x16x32_f16 (2 indep 4-chains per N-tile)
//   all D-rows equal -> lane L holds z[nt*16+(L&15)]; picks acc[L>>4]
//   => lane L owns unit 64w+L = threadIdx.x: coalesced xw load, 1 tanh,
//      1 contiguous ds_write_b16, 1 barrier. No shuffles.
// ---------------------------------------------------------------------------
__global__ __launch_bounds__(256, 1) void k_rnn(
    const _Float16* __restrict__ ufrag, const unsigned short* __restrict__ xw,
    const float* __restrict__ W1, const float* __restrict__ b1,
    const float* __restrict__ W2, const float* __restrict__ b2,
    float* __restrict__ out)
{
    __shared__ __align__(16) _Float16 hb[2][256];
    __shared__ float hid[32];
    const int t    = threadIdx.x;
    const int lane = t & 63;
    const int w    = t >> 6;
    const int kg   = lane >> 4;
    const int b    = blockIdx.x;

    // U B-frags -> registers: ufr[q][kt], tile nt = 4w+q. 32 x dwordx4, one-time.
    half8 ufr[4][8];
    #pragma unroll
    for (int q = 0; q < 4; q++) {
        #pragma unroll
        for (int kt = 0; kt < 8; kt++) {
            ufr[q][kt] = *(const half8*)(ufrag + ((size_t)(kt * 16 + (4 * w + q)) * 64 + lane) * 8);
        }
    }

    hb[0][t] = (_Float16)0.f;
    hb[1][t] = (_Float16)0.f;
    __syncthreads();

    const unsigned short* xp = xw + (size_t)b * TT * UN + t;  // coalesced per wave
    unsigned short x0 = xp[0];
    unsigned short x1 = xp[UN];
    int cur = 0;

    const float c3 = -0.33333334f, c5 = 0.13333334f, c7 = -0.05396825f, c9 = 0.02186949f;
    const floatx4 zero4 = {0.f, 0.f, 0.f, 0.f};

    for (int s = 0; s < TT; s++) {
        int sn = (s + 2 < TT) ? s + 2 : TT - 1;
        unsigned short x2 = xp[(size_t)sn * UN];

        // A-frags: lane reads h[kt*32 + kg*8 .. +8] (16-way broadcast, conflict-free)
        half8 afr[8];
        const _Float16* hbase = hb[cur] + kg * 8;
        #pragma unroll
        for (int kt = 0; kt < 8; kt++) {
            afr[kt] = *(const half8*)(hbase + kt * 32);
        }

        // z for this wave's 4 N-tiles; 2 independent chains per tile
        float z[4];
        #pragma unroll
        for (int q = 0; q < 4; q++) {
            floatx4 ae = zero4, ao = zero4;
            #pragma unroll
            for (int kt = 0; kt < 4; kt++) {
                ae = __builtin_amdgcn_mfma_f32_16x16x32_f16(afr[2 * kt],     ufr[q][2 * kt],     ae, 0, 0, 0);
                ao = __builtin_amdgcn_mfma_f32_16x16x32_f16(afr[2 * kt + 1], ufr[q][2 * kt + 1], ao, 0, 0, 0);
            }
            z[q] = ae[0] + ao[0];
        }

        // lane L owns unit 64w+L -> tile q = L>>4
        int sel = lane >> 4;
        float zz = (sel == 0) ? z[0] : (sel == 1) ? z[1] : (sel == 2) ? z[2] : z[3];
        zz += bf2f(x0);

        float hn;
        if (__builtin_expect(fabsf(zz) > 0.75f, 0)) {
            float e = __expf(2.f * zz);
            hn = 1.f - 2.f * __builtin_amdgcn_rcpf(e + 1.f);
        } else {
            float x2f = zz * zz;
            float p = fmaf(x2f, c9, c7);
            p = fmaf(x2f, p, c5);
            p = fmaf(x2f, p, c3);
            hn = fmaf(zz * x2f, p, zz);
        }

        hb[cur ^ 1][t] = (_Float16)hn;
        __syncthreads();
        cur ^= 1;
        x0 = x1;
        x1 = x2;
    }

    // ---- head: hidden = relu(h @ W1 + b1); logits; softmax
    if (t < 32) {
        float a = b1[t];
        for (int k = 0; k < 256; k++) a += (float)hb[cur][k] * W1[k * 32 + t];
        hid[t] = fmaxf(a, 0.f);
    }
    __syncthreads();
    if (t == 0) {
        float l0 = b2[0], l1 = b2[1];
        #pragma unroll
        for (int i = 0; i < 32; i++) {
            float hv = hid[i];
            l0 += hv * W2[2 * i];
            l1 += hv * W2[2 * i + 1];
        }
        float mx2 = fmaxf(l0, l1);
        float e0 = __expf(l0 - mx2), e1 = __expf(l1 - mx2);
        float inv = 1.f / (e0 + e1);
        out[2 * b]     = e0 * inv;
        out[2 * b + 1] = e1 * inv;
    }
}

extern "C" void kernel_launch(void* const* d_in, const int* in_sizes, int n_in,
                              void* d_out, int out_size, void* d_ws, size_t ws_size,
                              hipStream_t stream) {
    const int*   sent = (const int*)d_in[0];
    const float* emb  = (const float*)d_in[1];
    const float* W    = (const float*)d_in[2];
    const float* U    = (const float*)d_in[3];
    const float* W1   = (const float*)d_in[4];
    const float* b1   = (const float*)d_in[5];
    const float* W2   = (const float*)d_in[6];
    const float* b2   = (const float*)d_in[7];
    float* out = (float*)d_out;

    unsigned short* xw    = (unsigned short*)d_ws;                                        // 32 MB bf16 [B][T][U]
    unsigned short* wfrag = (unsigned short*)((char*)d_ws + (size_t)NB * TT * UN * 2);    // 128 KB
    _Float16*       ufrag = (_Float16*)((char*)d_ws + (size_t)NB * TT * UN * 2 + (size_t)UN * EM * 2); // 128 KB

    k_wfrag<<<32, 256, 0, stream>>>(W, wfrag);
    k_ufrag<<<32, 256, 0, stream>>>(U, ufrag);
    k_gemm<<<(NB * TT) / 64, 256, 0, stream>>>(sent, emb, wfrag, xw);
    k_rnn<<<NB, 256, 0, stream>>>(ufrag, xw, W1, b1, W2, b2, out);
}